// Round 2
// baseline (74525.873 us; speedup 1.0000x reference)
//
#include <hip/hip_runtime.h>
#include <hip/hip_cooperative_groups.h>

namespace cg = cooperative_groups;

#define BB 128
#define TT 512
#define DD 256
#define HH 512

#define WP0_FLOATS (2048 * 768)   // L0 packed weights
#define WP1_FLOATS (2048 * 1024)  // L1 packed weights

__device__ __forceinline__ float sig_(float x) { return 1.0f / (1.0f + __expf(-x)); }

// ---------------- projection GEMM: xp = x @ proj_w.T + proj_b ----------------
__global__ __launch_bounds__(256) void proj_kernel(const float* __restrict__ x,
                                                   const float* __restrict__ pw,
                                                   const float* __restrict__ pb,
                                                   float* __restrict__ xp) {
  __shared__ float At[64 * 68];
  __shared__ float Bt[64 * 68];
  const int bm = blockIdx.x >> 2;
  const int bn = blockIdx.x & 3;
  const int tid = threadIdx.x;
  const int rg = tid >> 4;
  const int cgi = tid & 15;
  const int m0 = bm * 64, n0 = bn * 64;
  float acc[4][4] = {};
  for (int kt = 0; kt < 4; ++kt) {
    const int k0 = kt * 64;
    {
      const int r = tid >> 2, q = tid & 3;
      const float4* src = (const float4*)(x + (size_t)(m0 + r) * DD + k0 + q * 16);
      float4* dst = (float4*)&At[r * 68 + q * 16];
#pragma unroll
      for (int j = 0; j < 4; ++j) dst[j] = src[j];
    }
    {
      const int n = tid & 63, kg = tid >> 6;
      const float4* src = (const float4*)(pw + (size_t)(n0 + n) * DD + k0 + kg * 16);
#pragma unroll
      for (int j = 0; j < 4; ++j) {
        float4 v = src[j];
        const int kk = kg * 16 + j * 4;
        Bt[(kk + 0) * 68 + n] = v.x;
        Bt[(kk + 1) * 68 + n] = v.y;
        Bt[(kk + 2) * 68 + n] = v.z;
        Bt[(kk + 3) * 68 + n] = v.w;
      }
    }
    __syncthreads();
#pragma unroll
    for (int k4 = 0; k4 < 64; k4 += 4) {
      float4 a[4], b[4];
#pragma unroll
      for (int j = 0; j < 4; ++j) a[j] = *(const float4*)&At[(rg * 4 + j) * 68 + k4];
#pragma unroll
      for (int j = 0; j < 4; ++j) b[j] = *(const float4*)&Bt[(k4 + j) * 68 + cgi * 4];
#pragma unroll
      for (int jr = 0; jr < 4; ++jr) {
#pragma unroll
        for (int q = 0; q < 4; ++q) {
          const float av = q == 0 ? a[jr].x : q == 1 ? a[jr].y : q == 2 ? a[jr].z : a[jr].w;
          acc[jr][0] = fmaf(av, b[q].x, acc[jr][0]);
          acc[jr][1] = fmaf(av, b[q].y, acc[jr][1]);
          acc[jr][2] = fmaf(av, b[q].z, acc[jr][2]);
          acc[jr][3] = fmaf(av, b[q].w, acc[jr][3]);
        }
      }
    }
    __syncthreads();
  }
  const float4 bias = *(const float4*)&pb[n0 + cgi * 4];
#pragma unroll
  for (int jr = 0; jr < 4; ++jr) {
    float4 o;
    o.x = acc[jr][0] + bias.x;
    o.y = acc[jr][1] + bias.y;
    o.z = acc[jr][2] + bias.z;
    o.w = acc[jr][3] + bias.w;
    *(float4*)&xp[(size_t)(m0 + rg * 4 + jr) * DD + n0 + cgi * 4] = o;
  }
}

// ---------------- weight pack ----------------
// wp[g8][k4][c][j]: colgroup g8 (8 gate-cols = 2 cells x 4 gates), c = cell_loc*4+gate.
// Source gate-row = gate*H + (g8*2 + cell_loc); k concatenates [x-part | h-part].
__global__ __launch_bounds__(256) void pack_w_kernel(
    const float* __restrict__ wx0, const float* __restrict__ wh0,
    const float* __restrict__ wx1, const float* __restrict__ wh1,
    float* __restrict__ wp0, float* __restrict__ wp1) {
  const int idx = blockIdx.x * 256 + threadIdx.x;
  if (idx < WP0_FLOATS) {
    const int j = idx & 3;
    const int c = (idx >> 2) & 7;
    const int k4 = (idx >> 5) % 192;
    const int g8 = (idx >> 5) / 192;
    const int k = k4 * 4 + j;
    const int row = (c & 3) * HH + g8 * 2 + (c >> 2);
    wp0[idx] = (k < DD) ? wx0[(size_t)row * DD + k] : wh0[(size_t)row * HH + (k - DD)];
  }
  if (idx < WP1_FLOATS) {
    const int j = idx & 3;
    const int c = (idx >> 2) & 7;
    const int k4 = (idx >> 5) & 255;
    const int g8 = (idx >> 5) >> 8;
    const int k = k4 * 4 + j;
    const int row = (c & 3) * HH + g8 * 2 + (c >> 2);
    wp1[idx] = (k < HH) ? wx1[(size_t)row * HH + k] : wh1[(size_t)row * HH + (k - HH)];
  }
}

// ---------------- persistent pipelined 2-layer LSTM ----------------
// 256 blocks x 256 threads (4 waves), cooperative, 1 block/CU.
// Block: role=layer, rowhalf (64 rows), 32 gate-cols; wave = colgroup of 8 gc.
// Lane <-> batch row. acc[8] per lane. W: wave-uniform broadcast loads from
// packed L2-resident stream, double-buffered one k8 (64 floats) ahead.
// A (x‖h) staged in LDS, one tile prefetched ahead; 1 b128 A-read feeds 32 FMA.

#define AP 68  // A-tile pitch (words): uniform bank use for both write & read

__global__ __launch_bounds__(256, 1) void lstm_kernel(
    const float* __restrict__ xp,
    const float* __restrict__ wp0, const float* __restrict__ wp1,
    const float* __restrict__ bx0, const float* __restrict__ bh0,
    const float* __restrict__ bx1, const float* __restrict__ bh1,
    float* __restrict__ h0buf, float* __restrict__ h1buf) {
  cg::grid_group grid = cg::this_grid();
  __shared__ float At[64 * AP];
  const int bidx = blockIdx.x;
  const int role = bidx >> 7;      // 0: layer0, 1: layer1
  const int lid = bidx & 127;
  const int m0 = (lid >> 6) * 64;  // row half
  const int gcblk = lid & 63;      // 32 gate-cols per block
  const int tid = threadIdx.x;
  const int w = tid >> 6;          // wave 0..3
  const int lane = tid & 63;       // lane <-> row m0+lane
  const int g8 = gcblk * 4 + w;    // global colgroup 0..255

  // zero initial h state (ws re-poisoned before every launch)
  for (int i = bidx * 256 + tid; i < 2 * BB * HH; i += 256 * 256) {
    h0buf[i] = 0.0f;
    h1buf[i] = 0.0f;
  }
  __threadfence();
  grid.sync();

  const float* wp = role ? wp1 : wp0;
  const float* bx = role ? bx1 : bx0;
  const float* bh = role ? bh1 : bh0;
  const int KX = role ? HH : DD;
  const int K = KX + HH;           // 768 or 1024
  const int ntiles = K >> 6;       // 12 or 16
  const int nk8 = K >> 3;          // 96 or 128
  const float* wpg = wp + (size_t)g8 * K * 8;  // this wave's packed stream

  float bg[8];
#pragma unroll
  for (int c = 0; c < 8; ++c) {
    const int gate = c & 3, cl = c >> 2;
    const int cg = g8 * 2 + cl;
    bg[c] = bx[gate * HH + cg] + bh[gate * HH + cg];
  }
  float cst[2] = {0.f, 0.f};

  const int srow = tid >> 2;  // staging: thread covers row srow, 16-float chunk sq
  const int sq = tid & 3;

  for (int p = 0; p <= TT; ++p) {
    const bool active = role ? (p >= 1) : (p < TT);
    if (active) {
      const int t = role ? (p - 1) : p;
      const int rdbuf = (p + 1) & 1;
      const int wrbuf = p & 1;
      const float* hprev = (role ? h1buf : h0buf) + (size_t)rdbuf * BB * HH;
      const float* xsrc;
      size_t xpitch;
      if (role) { xsrc = h0buf + (size_t)rdbuf * BB * HH; xpitch = HH; }
      else      { xsrc = xp + (size_t)t * DD;             xpitch = (size_t)TT * DD; }

      float acc[8] = {0.f, 0.f, 0.f, 0.f, 0.f, 0.f, 0.f, 0.f};

      // ---- A-tile staging prefetch (tile 0) ----
      float4 st[4];
      {
        const int ks = sq * 16;
        const float* s = (ks < KX) ? xsrc + (size_t)(m0 + srow) * xpitch + ks
                                   : hprev + (size_t)(m0 + srow) * HH + (ks - KX);
#pragma unroll
        for (int i = 0; i < 4; ++i) st[i] = ((const float4*)s)[i];
      }
      // ---- W prefetch (k8 = 0) ----
      float4 wcur[16], wnxt[16];
#pragma unroll
      for (int i = 0; i < 16; ++i) wcur[i] = ((const float4*)wpg)[i];
      int k8g = 0;

      for (int kt = 0; kt < ntiles; ++kt) {
        __syncthreads();  // previous tile consumed
        {
          float* d = &At[srow * AP + sq * 16];
#pragma unroll
          for (int i = 0; i < 4; ++i) ((float4*)d)[i] = st[i];
        }
        __syncthreads();
        // issue next tile's staging loads (overlap with compute below)
        if (kt + 1 < ntiles) {
          const int ks = ((kt + 1) << 6) + sq * 16;
          const float* s = (ks < KX) ? xsrc + (size_t)(m0 + srow) * xpitch + ks
                                     : hprev + (size_t)(m0 + srow) * HH + (ks - KX);
#pragma unroll
          for (int i = 0; i < 4; ++i) st[i] = ((const float4*)s)[i];
        }
        // ---- inner compute: 8 x k8 ----
#pragma unroll
        for (int k8 = 0; k8 < 8; ++k8) {
          const int nk = (k8g + 1 < nk8) ? (k8g + 1) : (nk8 - 1);
          const float4* s = (const float4*)(wpg + (size_t)nk * 64);
#pragma unroll
          for (int i = 0; i < 16; ++i) wnxt[i] = s[i];
          const float4 a0 = *(const float4*)&At[lane * AP + k8 * 8];
          const float4 a1 = *(const float4*)&At[lane * AP + k8 * 8 + 4];
#pragma unroll
          for (int c = 0; c < 8; ++c) {
            const float4 wA = wcur[c];
            const float4 wB = wcur[8 + c];
            acc[c] = fmaf(a0.x, wA.x, acc[c]);
            acc[c] = fmaf(a0.y, wA.y, acc[c]);
            acc[c] = fmaf(a0.z, wA.z, acc[c]);
            acc[c] = fmaf(a0.w, wA.w, acc[c]);
            acc[c] = fmaf(a1.x, wB.x, acc[c]);
            acc[c] = fmaf(a1.y, wB.y, acc[c]);
            acc[c] = fmaf(a1.z, wB.z, acc[c]);
            acc[c] = fmaf(a1.w, wB.w, acc[c]);
          }
#pragma unroll
          for (int i = 0; i < 16; ++i) wcur[i] = wnxt[i];
          ++k8g;
        }
      }
      // ---- cell update + h store (2 cells per lane) ----
      float* hout = (role ? h1buf : h0buf) + (size_t)wrbuf * BB * HH;
      float2 hv;
#pragma unroll
      for (int cl = 0; cl < 2; ++cl) {
        const float iv = acc[cl * 4 + 0] + bg[cl * 4 + 0];
        const float fv = acc[cl * 4 + 1] + bg[cl * 4 + 1];
        const float gv = acc[cl * 4 + 2] + bg[cl * 4 + 2];
        const float ov = acc[cl * 4 + 3] + bg[cl * 4 + 3];
        const float cn = sig_(fv) * cst[cl] + sig_(iv) * tanhf(gv);
        cst[cl] = cn;
        const float hnv = sig_(ov) * tanhf(cn);
        if (cl == 0) hv.x = hnv; else hv.y = hnv;
      }
      *(float2*)&hout[(size_t)(m0 + lane) * HH + g8 * 2] = hv;
    }
    __threadfence();
    grid.sync();
  }
}

// ---------------- head ----------------
__global__ __launch_bounds__(256) void head_kernel(const float* __restrict__ h1,
                                                   const float* __restrict__ fc1w,
                                                   const float* __restrict__ fc1b,
                                                   const float* __restrict__ fc2w,
                                                   const float* __restrict__ fc2b,
                                                   float* __restrict__ out) {
  __shared__ float part[256];
  __shared__ float hid[32];
  const int r = blockIdx.x;
  const int tid = threadIdx.x;
  const int c = tid & 31, pt = tid >> 5;
  const float4* ha = (const float4*)(h1 + (size_t)r * HH + pt * 64);
  const float4* wa = (const float4*)(fc1w + (size_t)c * HH + pt * 64);
  float s = 0.f;
#pragma unroll
  for (int j = 0; j < 16; ++j) {
    float4 av = ha[j], wv = wa[j];
    s = fmaf(av.x, wv.x, s);
    s = fmaf(av.y, wv.y, s);
    s = fmaf(av.z, wv.z, s);
    s = fmaf(av.w, wv.w, s);
  }
  part[tid] = s;
  __syncthreads();
  if (tid < 32) {
    float v = fc1b[tid];
#pragma unroll
    for (int q = 0; q < 8; ++q) v += part[q * 32 + tid];
    hid[tid] = fmaxf(v, 0.f);
  }
  __syncthreads();
  if (tid == 0) {
    float v = fc2b[0];
    for (int cc = 0; cc < 32; ++cc) v = fmaf(hid[cc], fc2w[cc], v);
    out[r] = v;
  }
}

extern "C" void kernel_launch(void* const* d_in, const int* in_sizes, int n_in,
                              void* d_out, int out_size, void* d_ws, size_t ws_size,
                              hipStream_t stream) {
  const float* x    = (const float*)d_in[0];
  const float* pw   = (const float*)d_in[1];
  const float* pb   = (const float*)d_in[2];
  const float* wx0  = (const float*)d_in[3];
  const float* bx0  = (const float*)d_in[4];
  const float* wh0  = (const float*)d_in[5];
  const float* bh0  = (const float*)d_in[6];
  const float* wx1  = (const float*)d_in[7];
  const float* bx1  = (const float*)d_in[8];
  const float* wh1  = (const float*)d_in[9];
  const float* bh1  = (const float*)d_in[10];
  const float* fc1w = (const float*)d_in[11];
  const float* fc1b = (const float*)d_in[12];
  const float* fc2w = (const float*)d_in[13];
  const float* fc2b = (const float*)d_in[14];
  float* out = (float*)d_out;

  // ws layout (floats): xp [B*T*D] | h0buf [2*B*H] | h1buf [2*B*H] | wp0 | wp1
  float* xp = (float*)d_ws;
  float* h0buf = xp + (size_t)BB * TT * DD;
  float* h1buf = h0buf + 2 * BB * HH;
  float* wp0 = h1buf + 2 * BB * HH;
  float* wp1 = wp0 + WP0_FLOATS;

  proj_kernel<<<dim3(4096), dim3(256), 0, stream>>>(x, pw, pb, xp);
  pack_w_kernel<<<dim3((WP1_FLOATS + 255) / 256), dim3(256), 0, stream>>>(
      wx0, wh0, wx1, wh1, wp0, wp1);

  void* kargs[] = {(void*)&xp,  (void*)&wp0, (void*)&wp1, (void*)&bx0,
                   (void*)&bh0, (void*)&bx1, (void*)&bh1, (void*)&h0buf,
                   (void*)&h1buf};
  hipLaunchCooperativeKernel((void*)lstm_kernel, dim3(256), dim3(256), kargs, 0,
                             stream);

  head_kernel<<<dim3(BB), dim3(256), 0, stream>>>(h1buf, fc1w, fc1b, fc2w, fc2b, out);
}